// Round 1
// baseline (163.356 us; speedup 1.0000x reference)
//
#include <hip/hip_runtime.h>
#include <hip/hip_bf16.h>
#include <hip/hip_fp8.h>

// Problem shape (fixed by setup_inputs)
#define SEQ   16384
#define DIN_  2048
#define DOUT_ 1024
#define NE_   8
#define TPE   (SEQ / NE_)   // 2048 tokens per expert

typedef __bf16 bf16x8 __attribute__((ext_vector_type(8)));
typedef __bf16 bf16x4 __attribute__((ext_vector_type(4)));
typedef float  f32x4  __attribute__((ext_vector_type(4)));

// async global->LDS, 16B per lane. LDS dest must be wave_base + lane*16 (linear).
#define GLD(gp, lp) __builtin_amdgcn_global_load_lds( \
    (const __attribute__((address_space(1))) unsigned int*)(gp), \
    (__attribute__((address_space(3))) unsigned int*)(lp), 16, 0, 0)

// Emulates reference fp8_round: clip(v/scale, +-448) -> e4m3fn (RNE, saturated) -> f32 -> *scale
__device__ __forceinline__ float fp8_round_dq(float v, float scale) {
    float r = v / scale;                       // IEEE div, matches jnp t/scale
    r = fminf(fmaxf(r, -448.0f), 448.0f);
    __hip_fp8_e4m3 q(r);                       // OCP e4m3fn, RNE
    return (float)q * scale;
}

// ---------------- activation quant-dequant: 1x128 tiles ----------------
// One block per row (2048 elems = 16 tiles). 16 lanes per tile, 8 floats/lane.
__global__ __launch_bounds__(256) void quant_x_kernel(const float* __restrict__ X,
                                                      __bf16* __restrict__ Xq) {
    const int row  = blockIdx.x;
    const int t    = threadIdx.x;
    const int lane = t & 63;
    const int wave = t >> 6;
    const int tile = wave * 4 + (lane >> 4);   // 0..15
    const int sub  = lane & 15;                // 0..15

    const float* p = X + (size_t)row * DIN_ + tile * 128 + sub * 8;
    float4 v0 = *(const float4*)p;
    float4 v1 = *(const float4*)(p + 4);

    float m = fmaxf(fmaxf(fmaxf(fabsf(v0.x), fabsf(v0.y)), fmaxf(fabsf(v0.z), fabsf(v0.w))),
                    fmaxf(fmaxf(fabsf(v1.x), fabsf(v1.y)), fmaxf(fabsf(v1.z), fabsf(v1.w))));
    // amax over the 16-lane group (tile)
    #pragma unroll
    for (int off = 1; off < 16; off <<= 1)
        m = fmaxf(m, __shfl_xor(m, off, 64));

    const float scale = fmaxf(m, 1e-12f) / 448.0f;

    bf16x8 o;
    o[0] = (__bf16)fp8_round_dq(v0.x, scale);
    o[1] = (__bf16)fp8_round_dq(v0.y, scale);
    o[2] = (__bf16)fp8_round_dq(v0.z, scale);
    o[3] = (__bf16)fp8_round_dq(v0.w, scale);
    o[4] = (__bf16)fp8_round_dq(v1.x, scale);
    o[5] = (__bf16)fp8_round_dq(v1.y, scale);
    o[6] = (__bf16)fp8_round_dq(v1.z, scale);
    o[7] = (__bf16)fp8_round_dq(v1.w, scale);
    *(bf16x8*)(Xq + (size_t)row * DIN_ + tile * 128 + sub * 8) = o;
}

// ---------------- weight quant-dequant: 128x128 blocks ----------------
// One 256-thread block per weight block. Each thread: 16 float4 (64 elems) held
// in registers across the amax reduction, then quant-dequant-store bf16.
__global__ __launch_bounds__(256) void quant_w_kernel(const float* __restrict__ W,
                                                      __bf16* __restrict__ Wq) {
    const int rb = blockIdx.x >> 4;    // 64 row-blocks (8192/128)
    const int cb = blockIdx.x & 15;    // 16 col-blocks (2048/128)
    const int t  = threadIdx.x;

    const float* base = W + (size_t)(rb * 128) * DIN_ + cb * 128;
    const int r0 = t >> 5;           // 0..7
    const int c0 = (t & 31) * 4;     // 0..124, 32 lanes cover one 128-float row

    float4 v[16];
    float m = 0.0f;
    #pragma unroll
    for (int i = 0; i < 16; ++i) {
        v[i] = *(const float4*)(base + (size_t)(i * 8 + r0) * DIN_ + c0);
        m = fmaxf(m, fmaxf(fmaxf(fabsf(v[i].x), fabsf(v[i].y)),
                           fmaxf(fabsf(v[i].z), fabsf(v[i].w))));
    }
    #pragma unroll
    for (int off = 1; off < 64; off <<= 1)
        m = fmaxf(m, __shfl_xor(m, off, 64));
    __shared__ float sm[4];
    if ((t & 63) == 0) sm[t >> 6] = m;
    __syncthreads();
    const float amax  = fmaxf(fmaxf(sm[0], sm[1]), fmaxf(sm[2], sm[3]));
    const float scale = fmaxf(amax, 1e-12f) / 448.0f;

    __bf16* obase = Wq + (size_t)(rb * 128) * DIN_ + cb * 128;
    #pragma unroll
    for (int i = 0; i < 16; ++i) {
        bf16x4 o;
        o[0] = (__bf16)fp8_round_dq(v[i].x, scale);
        o[1] = (__bf16)fp8_round_dq(v[i].y, scale);
        o[2] = (__bf16)fp8_round_dq(v[i].z, scale);
        o[3] = (__bf16)fp8_round_dq(v[i].w, scale);
        *(bf16x4*)(obase + (size_t)(i * 8 + r0) * DIN_ + c0) = o;
    }
}

// ---------------- grouped GEMM, m97 structure ----------------
// out[e*TPE + t, o] = sum_d Xq[e*TPE + t, d] * Wq[e*DOUT + o, d]
// 128x128 tile, BK=32, 4 waves (2x2), each wave 64x64 via 4x4 mfma 16x16x32 bf16.
__global__ __launch_bounds__(256, 2) void gemm_kernel(const __bf16* __restrict__ X,
                                                      const __bf16* __restrict__ W,
                                                      float* __restrict__ out) {
    __shared__ __bf16 As[128 * 32];
    __shared__ __bf16 Bs[128 * 32];

    const int bid  = blockIdx.x;
    const int e    = bid >> 7;        // 128 tiles per expert (16 x 8)
    const int rem  = bid & 127;
    const int brow = rem >> 3;        // 0..15
    const int bcol = rem & 7;         // 0..7

    const int t    = threadIdx.x;
    const int lane = t & 63;
    const int wave = t >> 6;
    const int wr   = wave >> 1, wc = wave & 1;

    const __bf16* Xt = X + (size_t)(e * TPE + brow * 128) * DIN_;
    const __bf16* Wt = W + (size_t)(e * DOUT_ + bcol * 128) * DIN_;

    // staging map: thread t -> row t/4 (and +64), k-chunk (t%4)*8
    const int srow = t >> 2;
    const int scol = (t & 3) * 8;

    const int frow = lane & 15;         // fragment row/col within 16
    const int fk   = (lane >> 4) * 8;   // k offset within 32

    f32x4 acc[4][4] = {};

    for (int k0 = 0; k0 < DIN_; k0 += 32) {
        __syncthreads();
        GLD(Xt + (size_t)srow * DIN_ + k0 + scol,        &As[t * 8]);
        GLD(Xt + (size_t)(srow + 64) * DIN_ + k0 + scol, &As[2048 + t * 8]);
        GLD(Wt + (size_t)srow * DIN_ + k0 + scol,        &Bs[t * 8]);
        GLD(Wt + (size_t)(srow + 64) * DIN_ + k0 + scol, &Bs[2048 + t * 8]);
        __syncthreads();

        bf16x8 a[4], b[4];
        #pragma unroll
        for (int m = 0; m < 4; ++m)
            a[m] = *(const bf16x8*)&As[(wr * 64 + m * 16 + frow) * 32 + fk];
        #pragma unroll
        for (int n = 0; n < 4; ++n)
            b[n] = *(const bf16x8*)&Bs[(wc * 64 + n * 16 + frow) * 32 + fk];

        #pragma unroll
        for (int m = 0; m < 4; ++m)
            #pragma unroll
            for (int n = 0; n < 4; ++n)
                acc[m][n] = __builtin_amdgcn_mfma_f32_16x16x32_bf16(a[m], b[n], acc[m][n], 0, 0, 0);
    }

    // epilogue: C/D mapping col = lane&15, row = (lane>>4)*4 + reg
    const int orow0 = e * TPE + brow * 128 + wr * 64;
    const int ocol0 = bcol * 128 + wc * 64;
    const int rlane = (lane >> 4) * 4;
    const int clane = lane & 15;
    #pragma unroll
    for (int m = 0; m < 4; ++m)
        #pragma unroll
        for (int n = 0; n < 4; ++n)
            #pragma unroll
            for (int j = 0; j < 4; ++j) {
                const int r = orow0 + m * 16 + rlane + j;
                const int c = ocol0 + n * 16 + clane;
                out[(size_t)r * DOUT_ + c] = acc[m][n][j];
            }
}

extern "C" void kernel_launch(void* const* d_in, const int* in_sizes, int n_in,
                              void* d_out, int out_size, void* d_ws, size_t ws_size,
                              hipStream_t stream) {
    const float* x = (const float*)d_in[0];
    // d_in[1] = tokens_per_expert: reference assumes equal split (reshape), so unused.
    const float* w = (const float*)d_in[2];
    float* out = (float*)d_out;

    // workspace: x_dq bf16 (64 MiB) + w_dq bf16 (32 MiB) = 96 MiB
    __bf16* xq = (__bf16*)d_ws;
    __bf16* wq = (__bf16*)((char*)d_ws + (size_t)SEQ * DIN_ * sizeof(__bf16));

    quant_x_kernel<<<SEQ, 256, 0, stream>>>(x, xq);
    quant_w_kernel<<<(NE_ * DOUT_ / 128) * (DIN_ / 128), 256, 0, stream>>>(w, wq);
    gemm_kernel<<<NE_ * (TPE / 128) * (DOUT_ / 128), 256, 0, stream>>>(xq, wq, out);
}

// Round 2
// 129.306 us; speedup vs baseline: 1.2633x; 1.2633x over previous
//
#include <hip/hip_runtime.h>
#include <hip/hip_bf16.h>
#include <hip/hip_fp8.h>

// Problem shape (fixed by setup_inputs)
#define SEQ   16384
#define DIN_  2048
#define DOUT_ 1024
#define NE_   8
#define TPE   (SEQ / NE_)   // 2048 tokens per expert
#define NT    (DIN_ / 64)   // 32 K-tiles of 64

typedef __bf16 bf16x8 __attribute__((ext_vector_type(8)));
typedef __bf16 bf16x4 __attribute__((ext_vector_type(4)));
typedef float  f32x4  __attribute__((ext_vector_type(4)));

// async global->LDS, 16B per lane. LDS dest must be wave-linear (base + lane*16).
#define GLD(gp, lp) __builtin_amdgcn_global_load_lds( \
    (const __attribute__((address_space(1))) unsigned int*)(gp), \
    (__attribute__((address_space(3))) unsigned int*)(lp), 16, 0, 0)

// Emulates reference fp8_round: clip(v/scale, +-448) -> e4m3fn (RNE, saturated) -> f32 -> *scale
__device__ __forceinline__ float fp8_round_dq(float v, float scale) {
    float r = v / scale;
    r = fminf(fmaxf(r, -448.0f), 448.0f);
    __hip_fp8_e4m3 q(r);
    return (float)q * scale;
}

// ---------------- activation quant-dequant: 1x128 tiles ----------------
__global__ __launch_bounds__(256) void quant_x_kernel(const float* __restrict__ X,
                                                      __bf16* __restrict__ Xq) {
    const int row  = blockIdx.x;
    const int t    = threadIdx.x;
    const int lane = t & 63;
    const int wave = t >> 6;
    const int tile = wave * 4 + (lane >> 4);   // 0..15
    const int sub  = lane & 15;                // 0..15

    const float* p = X + (size_t)row * DIN_ + tile * 128 + sub * 8;
    float4 v0 = *(const float4*)p;
    float4 v1 = *(const float4*)(p + 4);

    float m = fmaxf(fmaxf(fmaxf(fabsf(v0.x), fabsf(v0.y)), fmaxf(fabsf(v0.z), fabsf(v0.w))),
                    fmaxf(fmaxf(fabsf(v1.x), fabsf(v1.y)), fmaxf(fabsf(v1.z), fabsf(v1.w))));
    #pragma unroll
    for (int off = 1; off < 16; off <<= 1)
        m = fmaxf(m, __shfl_xor(m, off, 64));

    const float scale = fmaxf(m, 1e-12f) / 448.0f;

    bf16x8 o;
    o[0] = (__bf16)fp8_round_dq(v0.x, scale);
    o[1] = (__bf16)fp8_round_dq(v0.y, scale);
    o[2] = (__bf16)fp8_round_dq(v0.z, scale);
    o[3] = (__bf16)fp8_round_dq(v0.w, scale);
    o[4] = (__bf16)fp8_round_dq(v1.x, scale);
    o[5] = (__bf16)fp8_round_dq(v1.y, scale);
    o[6] = (__bf16)fp8_round_dq(v1.z, scale);
    o[7] = (__bf16)fp8_round_dq(v1.w, scale);
    *(bf16x8*)(Xq + (size_t)row * DIN_ + tile * 128 + sub * 8) = o;
}

// ---------------- weight quant-dequant: 128x128 blocks ----------------
__global__ __launch_bounds__(256) void quant_w_kernel(const float* __restrict__ W,
                                                      __bf16* __restrict__ Wq) {
    const int rb = blockIdx.x >> 4;
    const int cb = blockIdx.x & 15;
    const int t  = threadIdx.x;

    const float* base = W + (size_t)(rb * 128) * DIN_ + cb * 128;
    const int r0 = t >> 5;
    const int c0 = (t & 31) * 4;

    float4 v[16];
    float m = 0.0f;
    #pragma unroll
    for (int i = 0; i < 16; ++i) {
        v[i] = *(const float4*)(base + (size_t)(i * 8 + r0) * DIN_ + c0);
        m = fmaxf(m, fmaxf(fmaxf(fabsf(v[i].x), fabsf(v[i].y)),
                           fmaxf(fabsf(v[i].z), fabsf(v[i].w))));
    }
    #pragma unroll
    for (int off = 1; off < 64; off <<= 1)
        m = fmaxf(m, __shfl_xor(m, off, 64));
    __shared__ float sm[4];
    if ((t & 63) == 0) sm[t >> 6] = m;
    __syncthreads();
    const float amax  = fmaxf(fmaxf(sm[0], sm[1]), fmaxf(sm[2], sm[3]));
    const float scale = fmaxf(amax, 1e-12f) / 448.0f;

    __bf16* obase = Wq + (size_t)(rb * 128) * DIN_ + cb * 128;
    #pragma unroll
    for (int i = 0; i < 16; ++i) {
        bf16x4 o;
        o[0] = (__bf16)fp8_round_dq(v[i].x, scale);
        o[1] = (__bf16)fp8_round_dq(v[i].y, scale);
        o[2] = (__bf16)fp8_round_dq(v[i].z, scale);
        o[3] = (__bf16)fp8_round_dq(v[i].w, scale);
        *(bf16x4*)(obase + (size_t)(i * 8 + r0) * DIN_ + c0) = o;
    }
}

// ---------------- grouped GEMM: 256x256 tile, BK=64, 8-phase pipelined ----------------
// out[e*TPE + t, o] = sum_d Xq[e*TPE + t, d] * Wq[e*DOUT + o, d]
// 8 waves (2M x 4N), per-wave 128x64 out = acc[8][4] f32x4.
// LDS 128 KiB = 8 half-regions of [256 rows][32 k] bf16 (16 KiB each):
//   region(buf,kh): A at (buf*2+kh)*8192 elems, B at 32768 + (buf*2+kh)*8192.
// Half-tile sequence per K-tile kt: H=4kt+{0:B-kh0, 1:A-kh0, 2:B-kh1, 3:A-kh1}.
// Phase p of kt stages half 4kt+6+p; reads of a region always complete (barrier)
// before the GLD that overwrites it is issued. vmcnt(6) per K-tile boundary.
// Swizzle (T2): byte ^= ((byte>>7)&3)<<4 within each region (rows -> 16B slots).
__global__ __launch_bounds__(512, 2) void gemm_kernel(const __bf16* __restrict__ X,
                                                      const __bf16* __restrict__ W,
                                                      float* __restrict__ out) {
    __shared__ __bf16 lds[65536];   // 128 KiB

    // T1: bijective XCD swizzle; 256 blocks = 8 XCDs x 32 tiles = 1 expert/XCD
    const int bid  = blockIdx.x;
    const int wgid = (bid & 7) * 32 + (bid >> 3);
    const int e    = wgid >> 5;
    const int tile = wgid & 31;
    const int brow = tile >> 2;   // 8 row-tiles (256 rows)
    const int bcol = tile & 3;    // 4 col-tiles (256 cols)

    const int t     = threadIdx.x;
    const int lane  = t & 63;
    const int wave  = t >> 6;
    const int wm    = wave >> 2;  // 0..1
    const int wn    = wave & 3;   // 0..3
    const int flane = lane & 15;

    const __bf16* Xt = X + (size_t)(e * TPE + brow * 256) * DIN_;
    const __bf16* Wt = W + (size_t)(e * DOUT_ + bcol * 256) * DIN_;

    // stage one half-tile: 2 x GLD(16B) per thread, linear LDS dest, swizzled source
    auto stage_half = [&](int H) {
        if (H >= 4 * NT) return;
        const int kt2  = H >> 2;
        const int typ  = H & 3;          // 0:B-kh0 1:A-kh0 2:B-kh1 3:A-kh1
        const int kh   = typ >> 1;
        const bool isA = (typ & 1) != 0;
        const int buf  = kt2 & 1;
        const __bf16* src = isA ? Xt : Wt;
        const unsigned rbase = (isA ? 0u : 32768u) + (unsigned)(buf * 2 + kh) * 8192u;
        #pragma unroll
        for (int i = 0; i < 2; ++i) {
            const unsigned p = (unsigned)i * 8192u + (unsigned)t * 16u;  // byte off in region
            const unsigned q = p ^ (((p >> 7) & 3u) << 4);               // involution
            const unsigned srow = q >> 6;                                 // 0..255
            const unsigned scol = (q & 63u) >> 1;                         // elem 0..31
            GLD(src + (size_t)srow * DIN_ + kt2 * 64 + kh * 32 + scol,
                &lds[rbase + p / 2]);
        }
    };

    // swizzled fragment read: 16B at logical (row, 16B-slot lane>>4)
    auto ld_frag = [&](unsigned rbase, int row) -> bf16x8 {
        unsigned p = (unsigned)row * 64u + (unsigned)(lane >> 4) * 16u;
        p ^= ((p >> 7) & 3u) << 4;
        return *(const bf16x8*)&lds[rbase + p / 2];
    };

    f32x4 acc[8][4] = {};

    // prologue: issue halves 0..6; wait until halves 0..3 landed (K-tile 0 ready)
    stage_half(0); stage_half(1); stage_half(2); stage_half(3);
    stage_half(4); stage_half(5); stage_half(6);
    asm volatile("s_waitcnt vmcnt(6)" ::: "memory");
    __builtin_amdgcn_s_barrier();

    for (int kt = 0; kt < NT; ++kt) {
        const int buf = kt & 1;
        const unsigned A0 = (unsigned)(buf * 2 + 0) * 8192u;
        const unsigned A1 = (unsigned)(buf * 2 + 1) * 8192u;
        const unsigned B0 = 32768u + (unsigned)(buf * 2 + 0) * 8192u;
        const unsigned B1 = 32768u + (unsigned)(buf * 2 + 1) * 8192u;
        const int H0 = 4 * kt + 7;

        bf16x8 a[4], b[4];

        // ---- phase 1: kh0, m-frags 0-3 (8 ds_reads) ----
        #pragma unroll
        for (int n = 0; n < 4; ++n) b[n] = ld_frag(B0, wn * 64 + n * 16 + flane);
        #pragma unroll
        for (int m = 0; m < 4; ++m) a[m] = ld_frag(A0, wm * 128 + m * 16 + flane);
        stage_half(H0);
        __builtin_amdgcn_s_barrier();
        asm volatile("s_waitcnt lgkmcnt(0)" ::: "memory");
        __builtin_amdgcn_sched_barrier(0);
        __builtin_amdgcn_s_setprio(1);
        #pragma unroll
        for (int m = 0; m < 4; ++m)
            #pragma unroll
            for (int n = 0; n < 4; ++n)
                acc[m][n] = __builtin_amdgcn_mfma_f32_16x16x32_bf16(a[m], b[n], acc[m][n], 0, 0, 0);
        __builtin_amdgcn_s_setprio(0);
        __builtin_amdgcn_s_barrier();

        // ---- phase 2: kh0, m-frags 4-7 (4 ds_reads, B regs reused) ----
        #pragma unroll
        for (int m = 0; m < 4; ++m) a[m] = ld_frag(A0, wm * 128 + (m + 4) * 16 + flane);
        stage_half(H0 + 1);
        __builtin_amdgcn_s_barrier();
        asm volatile("s_waitcnt lgkmcnt(0)" ::: "memory");
        __builtin_amdgcn_sched_barrier(0);
        __builtin_amdgcn_s_setprio(1);
        #pragma unroll
        for (int m = 0; m < 4; ++m)
            #pragma unroll
            for (int n = 0; n < 4; ++n)
                acc[m + 4][n] = __builtin_amdgcn_mfma_f32_16x16x32_bf16(a[m], b[n], acc[m + 4][n], 0, 0, 0);
        __builtin_amdgcn_s_setprio(0);
        __builtin_amdgcn_s_barrier();

        // ---- phase 3: kh1, m-frags 0-3 (8 ds_reads) ----
        #pragma unroll
        for (int n = 0; n < 4; ++n) b[n] = ld_frag(B1, wn * 64 + n * 16 + flane);
        #pragma unroll
        for (int m = 0; m < 4; ++m) a[m] = ld_frag(A1, wm * 128 + m * 16 + flane);
        stage_half(H0 + 2);
        __builtin_amdgcn_s_barrier();
        asm volatile("s_waitcnt lgkmcnt(0)" ::: "memory");
        __builtin_amdgcn_sched_barrier(0);
        __builtin_amdgcn_s_setprio(1);
        #pragma unroll
        for (int m = 0; m < 4; ++m)
            #pragma unroll
            for (int n = 0; n < 4; ++n)
                acc[m][n] = __builtin_amdgcn_mfma_f32_16x16x32_bf16(a[m], b[n], acc[m][n], 0, 0, 0);
        __builtin_amdgcn_s_setprio(0);
        __builtin_amdgcn_s_barrier();

        // ---- phase 4: kh1, m-frags 4-7 (4 ds_reads) ----
        #pragma unroll
        for (int m = 0; m < 4; ++m) a[m] = ld_frag(A1, wm * 128 + (m + 4) * 16 + flane);
        stage_half(H0 + 3);
        __builtin_amdgcn_s_barrier();
        asm volatile("s_waitcnt lgkmcnt(0)" ::: "memory");
        __builtin_amdgcn_sched_barrier(0);
        __builtin_amdgcn_s_setprio(1);
        #pragma unroll
        for (int m = 0; m < 4; ++m)
            #pragma unroll
            for (int n = 0; n < 4; ++n)
                acc[m + 4][n] = __builtin_amdgcn_mfma_f32_16x16x32_bf16(a[m], b[n], acc[m + 4][n], 0, 0, 0);
        __builtin_amdgcn_s_setprio(0);
        // K-tile boundary: counted vmcnt (3 half-tiles stay in flight), drain at tail
        if (kt < NT - 2) {
            asm volatile("s_waitcnt vmcnt(6)" ::: "memory");
        } else {
            asm volatile("s_waitcnt vmcnt(0)" ::: "memory");
        }
        __builtin_amdgcn_s_barrier();
    }

    // epilogue: C/D mapping col = lane&15, row = (lane>>4)*4 + j
    const int orow0 = e * TPE + brow * 256 + wm * 128;
    const int ocol0 = bcol * 256 + wn * 64;
    const int rl = (lane >> 4) * 4;
    const int cl = lane & 15;
    #pragma unroll
    for (int m = 0; m < 8; ++m)
        #pragma unroll
        for (int n = 0; n < 4; ++n)
            #pragma unroll
            for (int j = 0; j < 4; ++j) {
                const int r = orow0 + m * 16 + rl + j;
                const int c = ocol0 + n * 16 + cl;
                out[(size_t)r * DOUT_ + c] = acc[m][n][j];
            }
}

extern "C" void kernel_launch(void* const* d_in, const int* in_sizes, int n_in,
                              void* d_out, int out_size, void* d_ws, size_t ws_size,
                              hipStream_t stream) {
    const float* x = (const float*)d_in[0];
    // d_in[1] = tokens_per_expert: reference assumes equal split, unused.
    const float* w = (const float*)d_in[2];
    float* out = (float*)d_out;

    __bf16* xq = (__bf16*)d_ws;
    __bf16* wq = (__bf16*)((char*)d_ws + (size_t)SEQ * DIN_ * sizeof(__bf16));

    quant_x_kernel<<<SEQ, 256, 0, stream>>>(x, xq);
    quant_w_kernel<<<(NE_ * DOUT_ / 128) * (DIN_ / 128), 256, 0, stream>>>(w, wq);
    gemm_kernel<<<NE_ * (TPE / 256) * (DOUT_ / 256), 512, 0, stream>>>(xq, wq, out);
}